// Round 6
// baseline (6099.358 us; speedup 1.0000x reference)
//
#include <hip/hip_runtime.h>

// LightGCN 3-layer propagation — R6: bf16 gather mirror + degree-sorted nodes.
//
// R5 post-mortem: ILP and nt-streaming both null -> props are bound by random
// gather line throughput and degree divergence (Poisson(7.1): wave runs
// E[max of 8] ~ 11 iters for 7 useful).
// R6: (a) bf16 mirror of each layer as gather source (halves gather bytes,
// 89 MB hot set; fp32 accumulate + fp32 outputs); (b) counting-sort nodes by
// degree -> uniform loop trip counts within a wave.

static constexpr int NUSERS = 500000;
static constexpr int NITEMS = 200000;
static constexpr int NNODES = 700000;   // NUSERS + NITEMS
static constexpr int NE     = 5000000;
static constexpr int SCAN_B = 1024;
static constexpr int NSB    = (NNODES + SCAN_B - 1) / SCAN_B;   // 684 scan blocks

typedef float f4 __attribute__((ext_vector_type(4)));   // native vec for nt ops

// round-to-nearest-even fp32 -> bf16 (as uint16 in low bits)
__device__ inline unsigned bf16rne(float f) {
    unsigned u = __float_as_uint(f);
    return (u + 0x7FFFu + ((u >> 16) & 1u)) >> 16;
}
__device__ inline unsigned packbf(float lo, float hi) {
    return bf16rne(lo) | (bf16rne(hi) << 16);
}

// --- int degree histogram over col -------------------------------------------
__global__ void k_hist(const int* __restrict__ col, int* __restrict__ deg) {
    int e = blockIdx.x * blockDim.x + threadIdx.x;
    if (e < NE) atomicAdd(&deg[col[e]], 1);
}

// --- per-block exclusive scan (Hillis-Steele in LDS) --------------------------
__global__ void k_scan1(const int* __restrict__ deg, int* __restrict__ offs,
                        int* __restrict__ bsums) {
    __shared__ int s[SCAN_B];
    int t = threadIdx.x;
    int i = blockIdx.x * SCAN_B + t;
    int v = (i < NNODES) ? deg[i] : 0;
    s[t] = v;
    __syncthreads();
    for (int off = 1; off < SCAN_B; off <<= 1) {
        int add = (t >= off) ? s[t - off] : 0;
        __syncthreads();
        s[t] += add;
        __syncthreads();
    }
    if (i < NNODES) offs[i] = s[t] - v;          // exclusive
    if (t == SCAN_B - 1) bsums[blockIdx.x] = s[t];
}

// --- scan the 684 block sums (single block) -----------------------------------
__global__ void k_scan2(int* __restrict__ bsums) {
    __shared__ int s[SCAN_B];
    int t = threadIdx.x;
    int v = (t < NSB) ? bsums[t] : 0;
    s[t] = v;
    __syncthreads();
    for (int off = 1; off < SCAN_B; off <<= 1) {
        int add = (t >= off) ? s[t - off] : 0;
        __syncthreads();
        s[t] += add;
        __syncthreads();
    }
    if (t < NSB) bsums[t] = s[t] - v;            // exclusive block offsets
}

// --- finalize offsets; init cursor copy; dinv ----------------------------------
__global__ void k_scan3(int* __restrict__ offs, const int* __restrict__ bsums,
                        int* __restrict__ cursor, const int* __restrict__ deg,
                        float* __restrict__ dinv) {
    int i = blockIdx.x * blockDim.x + threadIdx.x;
    if (i < NNODES) {
        int o = offs[i] + bsums[i >> 10];
        offs[i]   = o;
        cursor[i] = o;
        int d = deg[i];
        dinv[i] = (d > 0) ? rsqrtf((float)d) : 0.0f;
    }
    if (i == 0) offs[NNODES] = NE;
}

// --- degree-bucket histogram (256 buckets, clamp) ----------------------------
__global__ void k_dcount(const int* __restrict__ deg, int* __restrict__ dcnt) {
    int n = blockIdx.x * blockDim.x + threadIdx.x;
    if (n < NNODES) atomicAdd(&dcnt[min(deg[n], 255)], 1);
}

// --- scan 256 bucket counts -> cursor start ----------------------------------
__global__ void k_dscan(const int* __restrict__ dcnt, int* __restrict__ dcur) {
    __shared__ int s[256];
    int t = threadIdx.x;
    int v = dcnt[t];
    s[t] = v;
    __syncthreads();
    for (int off = 1; off < 256; off <<= 1) {
        int add = (t >= off) ? s[t - off] : 0;
        __syncthreads();
        s[t] += add;
        __syncthreads();
    }
    dcur[t] = s[t] - v;                          // exclusive
}

// --- scatter node ids into degree-sorted permutation -------------------------
__global__ void k_dscatter(const int* __restrict__ deg, int* __restrict__ dcur,
                           int* __restrict__ perm) {
    int n = blockIdx.x * blockDim.x + threadIdx.x;
    if (n >= NNODES) return;
    int pos = atomicAdd(&dcur[min(deg[n], 255)], 1);
    perm[pos] = n;
}

// --- scatter edges into col-sorted order: (row, w) packed 8B ------------------
__global__ void k_scatter(const int* __restrict__ row, const int* __restrict__ col,
                          const float* __restrict__ dinv, int* __restrict__ cursor,
                          int2* __restrict__ srw) {
    int e = blockIdx.x * blockDim.x + threadIdx.x;
    if (e >= NE) return;
    int r = row[e], c = col[e];
    int pos = atomicAdd(&cursor[c], 1);
    float w = dinv[r] * dinv[c];
    srw[pos] = make_int2(r, __float_as_int(w));
}

// --- init: layer-0 fp32 slot + bf16 mirror -----------------------------------
__global__ void k_init(const float4* __restrict__ user, const float4* __restrict__ item,
                       float4* __restrict__ all_emb, uint4* __restrict__ xb0) {
    int tid = blockIdx.x * blockDim.x + threadIdx.x;
    if (tid >= NNODES * 8) return;
    int n    = tid >> 3;
    int lane = tid & 7;
    const float4* s = ((n < NUSERS) ? user + (size_t)n * 16
                                    : item + (size_t)(n - NUSERS) * 16) + lane * 2;
    float4 a = s[0], b = s[1];
    float4* dst = all_emb + (size_t)n * 64 + lane * 2;
    dst[0] = a; dst[1] = b;
    uint4 o;
    o.x = packbf(a.x, a.y); o.y = packbf(a.z, a.w);
    o.z = packbf(b.x, b.y); o.w = packbf(b.z, b.w);
    xb0[(size_t)n * 8 + lane] = o;
}

// --- propagate layer L: bf16 gather, fp32 accumulate, degree-sorted ----------
// 8 threads per node, 8 dims each (one uint4 = 8 bf16 per edge per lane).
template <int L, bool FUSE_OUT>
__global__ void k_prop(const int* __restrict__ perm, const int* __restrict__ offs,
                       const int2* __restrict__ srw,
                       const uint4* __restrict__ xbp,   // bf16 source (layer L-1)
                       uint4* __restrict__ xbc,         // bf16 dest (layer L), unused L==3
                       float4* __restrict__ all_emb,
                       float* __restrict__ out_users, float* __restrict__ out_items) {
    int tid = blockIdx.x * blockDim.x + threadIdx.x;
    if (tid >= NNODES * 8) return;
    int g    = tid >> 3;
    int lane = tid & 7;                    // dims lane*8 .. lane*8+7
    int n = perm[g];
    int b = offs[n], e = offs[n + 1];
    float4 accA = make_float4(0.f, 0.f, 0.f, 0.f);
    float4 accB = make_float4(0.f, 0.f, 0.f, 0.f);
    const uint4* src = xbp + lane;

#define EDGE_FMA(rw)                                                          \
    {                                                                         \
        float w = __int_as_float((rw).y);                                     \
        uint4 q = src[(size_t)(rw).x * 8];                                    \
        accA.x += w * __uint_as_float(q.x << 16);                             \
        accA.y += w * __uint_as_float(q.x & 0xFFFF0000u);                     \
        accA.z += w * __uint_as_float(q.y << 16);                             \
        accA.w += w * __uint_as_float(q.y & 0xFFFF0000u);                     \
        accB.x += w * __uint_as_float(q.z << 16);                             \
        accB.y += w * __uint_as_float(q.z & 0xFFFF0000u);                     \
        accB.z += w * __uint_as_float(q.w << 16);                             \
        accB.w += w * __uint_as_float(q.w & 0xFFFF0000u);                     \
    }

    int k = b;
    for (; k + 4 <= e; k += 4) {
        int2 rw0 = srw[k + 0];
        int2 rw1 = srw[k + 1];
        int2 rw2 = srw[k + 2];
        int2 rw3 = srw[k + 3];
        EDGE_FMA(rw0); EDGE_FMA(rw1); EDGE_FMA(rw2); EDGE_FMA(rw3);
    }
    for (; k < e; ++k) {
        int2 rw = srw[k];
        EDGE_FMA(rw);
    }
#undef EDGE_FMA

    float4* dst = all_emb + (size_t)n * 64 + L * 16 + lane * 2;
    if constexpr (!FUSE_OUT) {
        dst[0] = accA;
        dst[1] = accB;
        uint4 o;
        o.x = packbf(accA.x, accA.y); o.y = packbf(accA.z, accA.w);
        o.z = packbf(accB.x, accB.y); o.w = packbf(accB.z, accB.w);
        xbc[(size_t)n * 8 + lane] = o;
    } else {
        const f4* p = reinterpret_cast<const f4*>(all_emb + (size_t)n * 64 + lane * 2);
        f4 x0a = __builtin_nontemporal_load(p + 0);
        f4 x0b = __builtin_nontemporal_load(p + 1);
        f4 x1a = __builtin_nontemporal_load(p + 16);
        f4 x1b = __builtin_nontemporal_load(p + 17);
        f4 x2a = __builtin_nontemporal_load(p + 32);
        f4 x2b = __builtin_nontemporal_load(p + 33);
        f4 aA = {accA.x, accA.y, accA.z, accA.w};
        f4 aB = {accB.x, accB.y, accB.z, accB.w};
        f4* dstn = reinterpret_cast<f4*>(dst);
        __builtin_nontemporal_store(aA, dstn + 0);
        __builtin_nontemporal_store(aB, dstn + 1);
        f4 ma = (x0a + x1a + x2a + aA) * 0.25f;
        f4 mb = (x0b + x1b + x2b + aB) * 0.25f;
        if (n < NUSERS) {
            f4* ou = reinterpret_cast<f4*>(out_users + (size_t)n * 64 + lane * 8);
            __builtin_nontemporal_store(ma, ou + 0);
            __builtin_nontemporal_store(mb, ou + 1);
        }
        if (n >= NITEMS) {
            f4* oi = reinterpret_cast<f4*>(out_items + (size_t)(n - NITEMS) * 64 + lane * 8);
            __builtin_nontemporal_store(ma, oi + 0);
            __builtin_nontemporal_store(mb, oi + 1);
        }
    }
}

extern "C" void kernel_launch(void* const* d_in, const int* in_sizes, int n_in,
                              void* d_out, int out_size, void* d_ws, size_t ws_size,
                              hipStream_t stream) {
    const float* user  = (const float*)d_in[0];
    const float* item  = (const float*)d_in[1];
    const int*   edges = (const int*)d_in[2];
    const int*   row = edges;            // edge_index[0]
    const int*   col = edges + NE;       // edge_index[1]

    float* out       = (float*)d_out;
    float* out_users = out;
    float* out_items = out + (size_t)NUSERS * 64;
    float* all_emb   = out + (size_t)NUSERS * 64 * 2;   // [700000][4][64]

    // workspace carve (~233 MB). 16B-aligned chunks first.
    char* ws = (char*)d_ws;
    uint4* xb0   = (uint4*)ws;                        ws += (size_t)NNODES * 128;  // bf16 [N][64]
    uint4* xb1   = (uint4*)ws;                        ws += (size_t)NNODES * 128;
    int2*  srw   = (int2*)ws;                         ws += (size_t)NE * 8;
    int*   deg   = (int*)ws;                          ws += (size_t)NNODES * 4;
    int*   offs  = (int*)ws;                          ws += (size_t)(NNODES + 1) * 4;
    int*   cursor= (int*)ws;                          ws += (size_t)NNODES * 4;
    int*   bsums = (int*)ws;                          ws += (size_t)SCAN_B * 4;
    float* dinv  = (float*)ws;                        ws += (size_t)NNODES * 4;
    int*   perm  = (int*)ws;                          ws += (size_t)NNODES * 4;
    int*   dcnt  = (int*)ws;                          ws += 256 * 4;
    int*   dcur  = (int*)ws;                          ws += 256 * 4;

    const int B = 256;
    const int prop_grid = (NNODES * 8 + B - 1) / B;

    (void)hipMemsetAsync(deg, 0, (size_t)NNODES * sizeof(int), stream);
    (void)hipMemsetAsync(dcnt, 0, 256 * sizeof(int), stream);
    k_hist    <<<(NE + B - 1) / B, B, 0, stream>>>(col, deg);
    k_scan1   <<<NSB, SCAN_B, 0, stream>>>(deg, offs, bsums);
    k_scan2   <<<1, SCAN_B, 0, stream>>>(bsums);
    k_scan3   <<<(NNODES + B - 1) / B, B, 0, stream>>>(offs, bsums, cursor, deg, dinv);
    k_dcount  <<<(NNODES + B - 1) / B, B, 0, stream>>>(deg, dcnt);
    k_dscan   <<<1, 256, 0, stream>>>(dcnt, dcur);
    k_dscatter<<<(NNODES + B - 1) / B, B, 0, stream>>>(deg, dcur, perm);
    k_scatter <<<(NE + B - 1) / B, B, 0, stream>>>(row, col, dinv, cursor, srw);
    k_init    <<<prop_grid, B, 0, stream>>>(
        (const float4*)user, (const float4*)item, (float4*)all_emb, xb0);

    k_prop<1, false><<<prop_grid, B, 0, stream>>>(perm, offs, srw, xb0, xb1,
                                                  (float4*)all_emb, nullptr, nullptr);
    k_prop<2, false><<<prop_grid, B, 0, stream>>>(perm, offs, srw, xb1, xb0,
                                                  (float4*)all_emb, nullptr, nullptr);
    k_prop<3, true> <<<prop_grid, B, 0, stream>>>(perm, offs, srw, xb0, nullptr,
                                                  (float4*)all_emb, out_users, out_items);
}

// Round 7
// 1245.282 us; speedup vs baseline: 4.8980x; 4.8980x over previous
//
#include <hip/hip_runtime.h>

// LightGCN 3-layer propagation — R7: R6 with LDS-privatized degree-bucket sort.
//
// R6 post-mortem: k_dcount/k_dscatter did 700K global atomics onto ~20 hot
// addresses (Poisson(7.1) degrees) -> 2.4ms each from same-address atomic
// serialization. Fix: per-block LDS histograms, one global atomic per
// bucket per block; in-bucket rank from LDS cursors (any in-bucket order is
// a valid permutation).

static constexpr int NUSERS = 500000;
static constexpr int NITEMS = 200000;
static constexpr int NNODES = 700000;   // NUSERS + NITEMS
static constexpr int NE     = 5000000;
static constexpr int SCAN_B = 1024;
static constexpr int NSB    = (NNODES + SCAN_B - 1) / SCAN_B;   // 684 scan blocks

typedef float f4 __attribute__((ext_vector_type(4)));   // native vec for nt ops

// round-to-nearest-even fp32 -> bf16 (as uint16 in low bits)
__device__ inline unsigned bf16rne(float f) {
    unsigned u = __float_as_uint(f);
    return (u + 0x7FFFu + ((u >> 16) & 1u)) >> 16;
}
__device__ inline unsigned packbf(float lo, float hi) {
    return bf16rne(lo) | (bf16rne(hi) << 16);
}

// --- int degree histogram over col -------------------------------------------
__global__ void k_hist(const int* __restrict__ col, int* __restrict__ deg) {
    int e = blockIdx.x * blockDim.x + threadIdx.x;
    if (e < NE) atomicAdd(&deg[col[e]], 1);
}

// --- per-block exclusive scan (Hillis-Steele in LDS) --------------------------
__global__ void k_scan1(const int* __restrict__ deg, int* __restrict__ offs,
                        int* __restrict__ bsums) {
    __shared__ int s[SCAN_B];
    int t = threadIdx.x;
    int i = blockIdx.x * SCAN_B + t;
    int v = (i < NNODES) ? deg[i] : 0;
    s[t] = v;
    __syncthreads();
    for (int off = 1; off < SCAN_B; off <<= 1) {
        int add = (t >= off) ? s[t - off] : 0;
        __syncthreads();
        s[t] += add;
        __syncthreads();
    }
    if (i < NNODES) offs[i] = s[t] - v;          // exclusive
    if (t == SCAN_B - 1) bsums[blockIdx.x] = s[t];
}

// --- scan the 684 block sums (single block) -----------------------------------
__global__ void k_scan2(int* __restrict__ bsums) {
    __shared__ int s[SCAN_B];
    int t = threadIdx.x;
    int v = (t < NSB) ? bsums[t] : 0;
    s[t] = v;
    __syncthreads();
    for (int off = 1; off < SCAN_B; off <<= 1) {
        int add = (t >= off) ? s[t - off] : 0;
        __syncthreads();
        s[t] += add;
        __syncthreads();
    }
    if (t < NSB) bsums[t] = s[t] - v;            // exclusive block offsets
}

// --- finalize offsets; init cursor copy; dinv ----------------------------------
__global__ void k_scan3(int* __restrict__ offs, const int* __restrict__ bsums,
                        int* __restrict__ cursor, const int* __restrict__ deg,
                        float* __restrict__ dinv) {
    int i = blockIdx.x * blockDim.x + threadIdx.x;
    if (i < NNODES) {
        int o = offs[i] + bsums[i >> 10];
        offs[i]   = o;
        cursor[i] = o;
        int d = deg[i];
        dinv[i] = (d > 0) ? rsqrtf((float)d) : 0.0f;
    }
    if (i == 0) offs[NNODES] = NE;
}

// --- degree-bucket histogram, LDS-privatized ---------------------------------
__global__ void k_dcount(const int* __restrict__ deg, int* __restrict__ dcnt) {
    __shared__ int h[256];
    int t = threadIdx.x;
    h[t] = 0;
    __syncthreads();
    for (int n = blockIdx.x * blockDim.x + t; n < NNODES; n += gridDim.x * blockDim.x)
        atomicAdd(&h[min(deg[n], 255)], 1);
    __syncthreads();
    if (h[t]) atomicAdd(&dcnt[t], h[t]);
}

// --- scan 256 bucket counts -> cursor start ----------------------------------
__global__ void k_dscan(const int* __restrict__ dcnt, int* __restrict__ dcur) {
    __shared__ int s[256];
    int t = threadIdx.x;
    int v = dcnt[t];
    s[t] = v;
    __syncthreads();
    for (int off = 1; off < 256; off <<= 1) {
        int add = (t >= off) ? s[t - off] : 0;
        __syncthreads();
        s[t] += add;
        __syncthreads();
    }
    dcur[t] = s[t] - v;                          // exclusive
}

// --- scatter node ids into degree-sorted perm, LDS-privatized ----------------
__global__ void k_dscatter(const int* __restrict__ deg, int* __restrict__ dcur,
                           int* __restrict__ perm) {
    __shared__ int lcnt[256];
    __shared__ int lbase[256];
    int t = threadIdx.x;
    lcnt[t] = 0;
    __syncthreads();
    int n = blockIdx.x * 256 + t;
    int bucket = 0, lrank = 0;
    if (n < NNODES) {
        bucket = min(deg[n], 255);
        lrank = atomicAdd(&lcnt[bucket], 1);     // LDS: in-block rank
    }
    __syncthreads();
    if (lcnt[t]) lbase[t] = atomicAdd(&dcur[t], lcnt[t]);  // one global atomic/bucket/block
    __syncthreads();
    if (n < NNODES) perm[lbase[bucket] + lrank] = n;
}

// --- scatter edges into col-sorted order: (row, w) packed 8B ------------------
__global__ void k_scatter(const int* __restrict__ row, const int* __restrict__ col,
                          const float* __restrict__ dinv, int* __restrict__ cursor,
                          int2* __restrict__ srw) {
    int e = blockIdx.x * blockDim.x + threadIdx.x;
    if (e >= NE) return;
    int r = row[e], c = col[e];
    int pos = atomicAdd(&cursor[c], 1);
    float w = dinv[r] * dinv[c];
    srw[pos] = make_int2(r, __float_as_int(w));
}

// --- init: layer-0 fp32 slot + bf16 mirror -----------------------------------
__global__ void k_init(const float4* __restrict__ user, const float4* __restrict__ item,
                       float4* __restrict__ all_emb, uint4* __restrict__ xb0) {
    int tid = blockIdx.x * blockDim.x + threadIdx.x;
    if (tid >= NNODES * 8) return;
    int n    = tid >> 3;
    int lane = tid & 7;
    const float4* s = ((n < NUSERS) ? user + (size_t)n * 16
                                    : item + (size_t)(n - NUSERS) * 16) + lane * 2;
    float4 a = s[0], b = s[1];
    float4* dst = all_emb + (size_t)n * 64 + lane * 2;
    dst[0] = a; dst[1] = b;
    uint4 o;
    o.x = packbf(a.x, a.y); o.y = packbf(a.z, a.w);
    o.z = packbf(b.x, b.y); o.w = packbf(b.z, b.w);
    xb0[(size_t)n * 8 + lane] = o;
}

// --- propagate layer L: bf16 gather, fp32 accumulate, degree-sorted ----------
// 8 threads per node, 8 dims each (one uint4 = 8 bf16 per edge per lane).
template <int L, bool FUSE_OUT>
__global__ void k_prop(const int* __restrict__ perm, const int* __restrict__ offs,
                       const int2* __restrict__ srw,
                       const uint4* __restrict__ xbp,   // bf16 source (layer L-1)
                       uint4* __restrict__ xbc,         // bf16 dest (layer L), unused L==3
                       float4* __restrict__ all_emb,
                       float* __restrict__ out_users, float* __restrict__ out_items) {
    int tid = blockIdx.x * blockDim.x + threadIdx.x;
    if (tid >= NNODES * 8) return;
    int g    = tid >> 3;
    int lane = tid & 7;                    // dims lane*8 .. lane*8+7
    int n = perm[g];
    int b = offs[n], e = offs[n + 1];
    float4 accA = make_float4(0.f, 0.f, 0.f, 0.f);
    float4 accB = make_float4(0.f, 0.f, 0.f, 0.f);
    const uint4* src = xbp + lane;

#define EDGE_FMA(rw)                                                          \
    {                                                                         \
        float w = __int_as_float((rw).y);                                     \
        uint4 q = src[(size_t)(rw).x * 8];                                    \
        accA.x += w * __uint_as_float(q.x << 16);                             \
        accA.y += w * __uint_as_float(q.x & 0xFFFF0000u);                     \
        accA.z += w * __uint_as_float(q.y << 16);                             \
        accA.w += w * __uint_as_float(q.y & 0xFFFF0000u);                     \
        accB.x += w * __uint_as_float(q.z << 16);                             \
        accB.y += w * __uint_as_float(q.z & 0xFFFF0000u);                     \
        accB.z += w * __uint_as_float(q.w << 16);                             \
        accB.w += w * __uint_as_float(q.w & 0xFFFF0000u);                     \
    }

    int k = b;
    for (; k + 4 <= e; k += 4) {
        int2 rw0 = srw[k + 0];
        int2 rw1 = srw[k + 1];
        int2 rw2 = srw[k + 2];
        int2 rw3 = srw[k + 3];
        EDGE_FMA(rw0); EDGE_FMA(rw1); EDGE_FMA(rw2); EDGE_FMA(rw3);
    }
    for (; k < e; ++k) {
        int2 rw = srw[k];
        EDGE_FMA(rw);
    }
#undef EDGE_FMA

    float4* dst = all_emb + (size_t)n * 64 + L * 16 + lane * 2;
    if constexpr (!FUSE_OUT) {
        dst[0] = accA;
        dst[1] = accB;
        uint4 o;
        o.x = packbf(accA.x, accA.y); o.y = packbf(accA.z, accA.w);
        o.z = packbf(accB.x, accB.y); o.w = packbf(accB.z, accB.w);
        xbc[(size_t)n * 8 + lane] = o;
    } else {
        const f4* p = reinterpret_cast<const f4*>(all_emb + (size_t)n * 64 + lane * 2);
        f4 x0a = __builtin_nontemporal_load(p + 0);
        f4 x0b = __builtin_nontemporal_load(p + 1);
        f4 x1a = __builtin_nontemporal_load(p + 16);
        f4 x1b = __builtin_nontemporal_load(p + 17);
        f4 x2a = __builtin_nontemporal_load(p + 32);
        f4 x2b = __builtin_nontemporal_load(p + 33);
        f4 aA = {accA.x, accA.y, accA.z, accA.w};
        f4 aB = {accB.x, accB.y, accB.z, accB.w};
        f4* dstn = reinterpret_cast<f4*>(dst);
        __builtin_nontemporal_store(aA, dstn + 0);
        __builtin_nontemporal_store(aB, dstn + 1);
        f4 ma = (x0a + x1a + x2a + aA) * 0.25f;
        f4 mb = (x0b + x1b + x2b + aB) * 0.25f;
        if (n < NUSERS) {
            f4* ou = reinterpret_cast<f4*>(out_users + (size_t)n * 64 + lane * 8);
            __builtin_nontemporal_store(ma, ou + 0);
            __builtin_nontemporal_store(mb, ou + 1);
        }
        if (n >= NITEMS) {
            f4* oi = reinterpret_cast<f4*>(out_items + (size_t)(n - NITEMS) * 64 + lane * 8);
            __builtin_nontemporal_store(ma, oi + 0);
            __builtin_nontemporal_store(mb, oi + 1);
        }
    }
}

extern "C" void kernel_launch(void* const* d_in, const int* in_sizes, int n_in,
                              void* d_out, int out_size, void* d_ws, size_t ws_size,
                              hipStream_t stream) {
    const float* user  = (const float*)d_in[0];
    const float* item  = (const float*)d_in[1];
    const int*   edges = (const int*)d_in[2];
    const int*   row = edges;            // edge_index[0]
    const int*   col = edges + NE;       // edge_index[1]

    float* out       = (float*)d_out;
    float* out_users = out;
    float* out_items = out + (size_t)NUSERS * 64;
    float* all_emb   = out + (size_t)NUSERS * 64 * 2;   // [700000][4][64]

    // workspace carve (~233 MB). 16B-aligned chunks first.
    char* ws = (char*)d_ws;
    uint4* xb0   = (uint4*)ws;                        ws += (size_t)NNODES * 128;  // bf16 [N][64]
    uint4* xb1   = (uint4*)ws;                        ws += (size_t)NNODES * 128;
    int2*  srw   = (int2*)ws;                         ws += (size_t)NE * 8;
    int*   deg   = (int*)ws;                          ws += (size_t)NNODES * 4;
    int*   offs  = (int*)ws;                          ws += (size_t)(NNODES + 1) * 4;
    int*   cursor= (int*)ws;                          ws += (size_t)NNODES * 4;
    int*   bsums = (int*)ws;                          ws += (size_t)SCAN_B * 4;
    float* dinv  = (float*)ws;                        ws += (size_t)NNODES * 4;
    int*   perm  = (int*)ws;                          ws += (size_t)NNODES * 4;
    int*   dcnt  = (int*)ws;                          ws += 256 * 4;
    int*   dcur  = (int*)ws;                          ws += 256 * 4;

    const int B = 256;
    const int prop_grid = (NNODES * 8 + B - 1) / B;

    (void)hipMemsetAsync(deg, 0, (size_t)NNODES * sizeof(int), stream);
    (void)hipMemsetAsync(dcnt, 0, 256 * sizeof(int), stream);
    k_hist    <<<(NE + B - 1) / B, B, 0, stream>>>(col, deg);
    k_scan1   <<<NSB, SCAN_B, 0, stream>>>(deg, offs, bsums);
    k_scan2   <<<1, SCAN_B, 0, stream>>>(bsums);
    k_scan3   <<<(NNODES + B - 1) / B, B, 0, stream>>>(offs, bsums, cursor, deg, dinv);
    k_dcount  <<<1024, 256, 0, stream>>>(deg, dcnt);
    k_dscan   <<<1, 256, 0, stream>>>(dcnt, dcur);
    k_dscatter<<<(NNODES + 255) / 256, 256, 0, stream>>>(deg, dcur, perm);
    k_scatter <<<(NE + B - 1) / B, B, 0, stream>>>(row, col, dinv, cursor, srw);
    k_init    <<<prop_grid, B, 0, stream>>>(
        (const float4*)user, (const float4*)item, (float4*)all_emb, xb0);

    k_prop<1, false><<<prop_grid, B, 0, stream>>>(perm, offs, srw, xb0, xb1,
                                                  (float4*)all_emb, nullptr, nullptr);
    k_prop<2, false><<<prop_grid, B, 0, stream>>>(perm, offs, srw, xb1, xb0,
                                                  (float4*)all_emb, nullptr, nullptr);
    k_prop<3, true> <<<prop_grid, B, 0, stream>>>(perm, offs, srw, xb0, nullptr,
                                                  (float4*)all_emb, out_users, out_items);
}